// Round 1
// baseline (603.105 us; speedup 1.0000x reference)
//
#include <hip/hip_runtime.h>

#define H 128
#define MAXLEN 431
#define BB 2048

// ws layout (floats): [0..127]=u2, [128..255]=u1, [256]=c, [384..2431]=hdot[b]

__global__ void prep_uv(const float* __restrict__ attn_w,
                        const float* __restrict__ attn_b,
                        const float* __restrict__ v,
                        float* __restrict__ ws) {
    int h = threadIdx.x;  // 128 threads
    float u1 = 0.f, u2 = 0.f;
    for (int e = 0; e < H; ++e) {
        float ve = v[e];
        u1 += ve * attn_w[e * 2 * H + h];        // w1[e,h]
        u2 += ve * attn_w[e * 2 * H + H + h];    // w2[e,h]
    }
    ws[h]     = u2;
    ws[H + h] = u1;
    if (h == 0) {
        float c = 0.f;
        for (int e = 0; e < H; ++e) c += attn_b[e] * v[e];
        ws[256] = c;
    }
}

__global__ void prep_hdot(const float* __restrict__ hidden,
                          float* __restrict__ ws) {
    int b = blockIdx.x * blockDim.x + threadIdx.x;  // 2048 total
    if (b >= BB) return;
    const float4* h4  = (const float4*)(hidden) + b * (H / 4);
    const float4* u14 = (const float4*)(ws + H);
    float a = 0.f;
    #pragma unroll
    for (int j = 0; j < H / 4; ++j) {
        float4 hv = h4[j];
        float4 uv = u14[j];
        a += hv.x * uv.x + hv.y * uv.y + hv.z * uv.z + hv.w * uv.w;
    }
    ws[384 + b] = a + ws[256];
}

// Each wave processes 4 rows (two 1024B fully-coalesced float4 loads) per iter.
// Lanes 0..31 cover one row, 32..63 the next; 5-step shfl_xor butterfly
// reduces each half-wave's 4-element partial dots into full 128-dots.
__global__ void main_scores(const float* __restrict__ k_emb,
                            const float* __restrict__ ws,
                            float* __restrict__ out) {
    const int lane = threadIdx.x & 63;
    const int sub  = lane & 31;
    const int half = lane >> 5;
    const float4 u2v = *((const float4*)ws + sub);   // u2[sub*4 .. sub*4+3]
    const float* hdot = ws + 384;

    long long wid = (long long)blockIdx.x * (blockDim.x >> 6) + (threadIdx.x >> 6);
    long long nw  = (long long)gridDim.x * (blockDim.x >> 6);
    const long long NQUAD = (long long)MAXLEN * BB / 4;  // 220672 groups of 4 rows

    for (long long q = wid; q < NQUAD; q += nw) {
        const float4* base = (const float4*)(k_emb + q * 512) + lane;
        float4 x0 = base[0];     // rows 4q, 4q+1
        float4 x1 = base[64];    // rows 4q+2, 4q+3
        float p0 = x0.x * u2v.x + x0.y * u2v.y + x0.z * u2v.z + x0.w * u2v.w;
        float p1 = x1.x * u2v.x + x1.y * u2v.y + x1.z * u2v.z + x1.w * u2v.w;
        #pragma unroll
        for (int off = 16; off >= 1; off >>= 1) {
            p0 += __shfl_xor(p0, off);
            p1 += __shfl_xor(p1, off);
        }
        if (sub == 0) {
            int row0 = (int)(q * 4) + half;       // rows 4q+half
            int row1 = row0 + 2;                  // rows 4q+2+half
            int l0 = row0 >> 11, b0 = row0 & (BB - 1);
            int l1 = row1 >> 11, b1 = row1 & (BB - 1);
            out[(long long)b0 * MAXLEN + l0] = p0 + hdot[b0];
            out[(long long)b1 * MAXLEN + l1] = p1 + hdot[b1];
        }
    }
}

extern "C" void kernel_launch(void* const* d_in, const int* in_sizes, int n_in,
                              void* d_out, int out_size, void* d_ws, size_t ws_size,
                              hipStream_t stream) {
    const float* hidden = (const float*)d_in[0];   // (1, 2048, 128)
    const float* k_emb  = (const float*)d_in[1];   // (431, 2048, 128)
    const float* attn_w = (const float*)d_in[2];   // (128, 256)
    const float* attn_b = (const float*)d_in[3];   // (128,)
    const float* v      = (const float*)d_in[4];   // (1, 128)
    float* out = (float*)d_out;                    // (2048, 431)
    float* ws  = (float*)d_ws;

    prep_uv<<<1, 128, 0, stream>>>(attn_w, attn_b, v, ws);
    prep_hdot<<<8, 256, 0, stream>>>(hidden, ws);
    main_scores<<<2048, 256, 0, stream>>>(k_emb, ws, out);
}